// Round 4
// baseline (3518.933 us; speedup 1.0000x reference)
//
#include <hip/hip_runtime.h>
#include <hip/hip_fp16.h>

#define N_NODES 25000
#define N_EDGES 400000
#define EPS_F 1e-5f

// WE chunk-plane layout: plane c (c=0..6) holds outputs [c*32, c*32+32) of all
// edges: half value at  WE[c*PL + e*32 + idx],  PL = N_EDGES*32.
#define PL ((size_t)N_EDGES * 32)

__device__ __forceinline__ float silu_f(float x) {
    return x / (1.0f + __expf(-x));
}

// ---------------------------------------------------------------------------
// K1: per-node linear transforms (node-per-lane; weight reads are uniform ->
// scalar loads; node row lives in VGPRs with static indexing only).
// XS/SC row layout (stride 192 f32): [0..63]=s, [64 + v*4 + c]=v (c<3, pad).
// ---------------------------------------------------------------------------
__global__ __launch_bounds__(256) void k_node_pre(
    const float* __restrict__ nh,
    const float* __restrict__ W1_0, const float* __restrict__ W1_1,
    const float* __restrict__ Wsc0, const float* __restrict__ Wsc1,
    float* __restrict__ XS, float* __restrict__ SC)
{
    int n = blockIdx.x * 256 + threadIdx.x;
    if (n >= N_NODES) return;
    const float* row = nh + (size_t)n * 160;
    float* xsrow = XS + (size_t)n * 192;
    float* scrow = SC + (size_t)n * 192;

    // ---- scalar channels ----
    float si[64];
#pragma unroll
    for (int m = 0; m < 16; ++m) {
        float4 t = *(const float4*)(row + m * 4);
        si[4*m+0] = t.x; si[4*m+1] = t.y; si[4*m+2] = t.z; si[4*m+3] = t.w;
    }
#pragma unroll 1
    for (int jg = 0; jg < 16; ++jg) {
        float a0=0,a1=0,a2=0,a3=0,b0=0,b1=0,b2=0,b3=0;
#pragma unroll
        for (int k = 0; k < 64; ++k) {
            float wa[4]; *(float4*)wa = *(const float4*)(W1_0 + k*64 + jg*4);
            float wb[4]; *(float4*)wb = *(const float4*)(Wsc0 + k*64 + jg*4);
            float s = si[k];
            a0 += s*wa[0]; a1 += s*wa[1]; a2 += s*wa[2]; a3 += s*wa[3];
            b0 += s*wb[0]; b1 += s*wb[1]; b2 += s*wb[2]; b3 += s*wb[3];
        }
        const float sc8 = 0.125f; // 1/sqrt(64)
        *(float4*)(xsrow + jg*4) = make_float4(a0*sc8, a1*sc8, a2*sc8, a3*sc8);
        *(float4*)(scrow + jg*4) = make_float4(b0*sc8, b1*sc8, b2*sc8, b3*sc8);
    }

    // ---- vector channels: v_in[u][c] = row[64 + u*3 + c] ----
    float vi[96];
#pragma unroll
    for (int m = 0; m < 24; ++m) {
        float4 t = *(const float4*)(row + 64 + m * 4);
        vi[4*m+0] = t.x; vi[4*m+1] = t.y; vi[4*m+2] = t.z; vi[4*m+3] = t.w;
    }
    const float is32 = 0.17677669529663687f; // 1/sqrt(32)
#pragma unroll 1
    for (int vg = 0; vg < 8; ++vg) {
        float a[4][3], b[4][3];
#pragma unroll
        for (int m = 0; m < 4; ++m) { a[m][0]=a[m][1]=a[m][2]=0.f; b[m][0]=b[m][1]=b[m][2]=0.f; }
#pragma unroll
        for (int u = 0; u < 32; ++u) {
            float wa[4]; *(float4*)wa = *(const float4*)(W1_1 + u*32 + vg*4);
            float wb[4]; *(float4*)wb = *(const float4*)(Wsc1 + u*32 + vg*4);
            float vx = vi[u*3+0], vy = vi[u*3+1], vz = vi[u*3+2];
#pragma unroll
            for (int m = 0; m < 4; ++m) {
                a[m][0] += vx*wa[m]; a[m][1] += vy*wa[m]; a[m][2] += vz*wa[m];
                b[m][0] += vx*wb[m]; b[m][1] += vy*wb[m]; b[m][2] += vz*wb[m];
            }
        }
#pragma unroll
        for (int m = 0; m < 4; ++m) {
            int v = vg*4 + m;
            *(float4*)(xsrow + 64 + v*4) = make_float4(a[m][0]*is32, a[m][1]*is32, a[m][2]*is32, 0.f);
            *(float4*)(scrow + 64 + v*4) = make_float4(b[m][0]*is32, b[m][1]*is32, b[m][2]*is32, 0.f);
        }
    }
}

// ---------------------------------------------------------------------------
// K2: per-src edge lists. Only int atomics (400k).
// ---------------------------------------------------------------------------
__global__ __launch_bounds__(256) void k_build_lists(
    const int* __restrict__ ei, int* __restrict__ CNT, int* __restrict__ LIST)
{
    int e = blockIdx.x * 256 + threadIdx.x;
    if (e >= N_EDGES) return;
    int src = ei[e];                       // row 0 = edge_src
    int pos = atomicAdd(&CNT[src], 1);
    if (pos < 64) LIST[src*64 + pos] = e;
}

// ---------------------------------------------------------------------------
// K3: FUSED edge MLP (edge-per-lane). NO LDS (occupancy -> VGPR-bound so the
// uniform L1/L2 weight-load latency is hidden by waves). Output in chunk-plane
// layout: each lane stores its own contiguous 64-B chunk (4 back-to-back
// uint4) -> full-line write-combining in L2, no RMW fetch (R3: FETCH 346 MB).
// ---------------------------------------------------------------------------
__global__ __launch_bounds__(256) void k_edge_mlp(
    const float* __restrict__ eat,
    const float* __restrict__ Wfc1, const float* __restrict__ Wfc2,
    const float* __restrict__ Wfc3,
    __half* __restrict__ WE)
{
    size_t e = (size_t)blockIdx.x * 256 + threadIdx.x;
    if (e >= N_EDGES) return;

    float av[8];
    *(float4*)(av+0) = *(const float4*)(eat + e*8);
    *(float4*)(av+4) = *(const float4*)(eat + e*8 + 4);
    const float is8 = 0.35355339059327373f; // 1/sqrt(8)

    // ---- layer 1: 8 -> 64, silu ----
    float h1[64];
#pragma unroll
    for (int jg = 0; jg < 16; ++jg) {
        float c0=0,c1=0,c2=0,c3=0;
#pragma unroll
        for (int k = 0; k < 8; ++k) {
            float w[4]; *(float4*)w = *(const float4*)(Wfc1 + k*64 + jg*4);
            float hk = av[k];
            c0 += hk*w[0]; c1 += hk*w[1]; c2 += hk*w[2]; c3 += hk*w[3];
        }
        h1[jg*4+0] = silu_f(c0*is8);
        h1[jg*4+1] = silu_f(c1*is8);
        h1[jg*4+2] = silu_f(c2*is8);
        h1[jg*4+3] = silu_f(c3*is8);
    }

    // ---- layer 2: 64 -> 64, silu ----
    float h2[64];
#pragma unroll 1
    for (int jg = 0; jg < 16; ++jg) {
        float c0=0,c1=0,c2=0,c3=0;
#pragma unroll
        for (int k = 0; k < 64; ++k) {
            float w[4]; *(float4*)w = *(const float4*)(Wfc2 + k*64 + jg*4);
            float hk = h1[k];
            c0 += hk*w[0]; c1 += hk*w[1]; c2 += hk*w[2]; c3 += hk*w[3];
        }
        h2[jg*4+0] = silu_f(c0*0.125f);
        h2[jg*4+1] = silu_f(c1*0.125f);
        h2[jg*4+2] = silu_f(c2*0.125f);
        h2[jg*4+3] = silu_f(c3*0.125f);
    }

    // ---- layer 3: 64 -> 224, fp16, 7 chunks of 32 outputs (64 B each) ----
#pragma unroll 1
    for (int c = 0; c < 7; ++c) {
        uint2 outp[8];
#pragma unroll
        for (int j = 0; j < 8; ++j) {
            int jg = c*8 + j;
            float c0=0,c1=0,c2=0,c3=0;
#pragma unroll
            for (int k = 0; k < 64; ++k) {
                float w[4]; *(float4*)w = *(const float4*)(Wfc3 + k*224 + jg*4);
                float hk = h2[k];
                c0 += hk*w[0]; c1 += hk*w[1]; c2 += hk*w[2]; c3 += hk*w[3];
            }
            __half2 p0 = __floats2half2_rn(c0*0.125f, c1*0.125f);
            __half2 p1 = __floats2half2_rn(c2*0.125f, c3*0.125f);
            outp[j] = make_uint2(*(unsigned int*)&p0, *(unsigned int*)&p1);
        }
        __half* wout = WE + (size_t)c*PL + e*32;   // 64-B aligned chunk
        *(uint4*)(wout +  0) = make_uint4(outp[0].x,outp[0].y,outp[1].x,outp[1].y);
        *(uint4*)(wout +  8) = make_uint4(outp[2].x,outp[2].y,outp[3].x,outp[3].y);
        *(uint4*)(wout + 16) = make_uint4(outp[4].x,outp[4].y,outp[5].x,outp[5].y);
        *(uint4*)(wout + 24) = make_uint4(outp[6].x,outp[6].y,outp[7].x,outp[7].y);
    }
}

// ---------------------------------------------------------------------------
// K4: wave-per-node gather + tensor product + segment sum (register
// accumulators, NO float atomics). Neighbor loop is software-pipelined:
// next edge's sh/w/xd loads issue (as raw bits) before current compute.
// Epilogue GEMMs read W2_0/W2_1 directly from global (L1-resident, once per
// node) — LDS is only the 7.9-KB accumulator tile, so occupancy is VGPR-bound.
// ---------------------------------------------------------------------------
__global__ __launch_bounds__(256) void k_aggregate(
    const int* __restrict__ ei, const float* __restrict__ esh,
    const __half* __restrict__ WE, const float* __restrict__ XS,
    const float* __restrict__ SC, const int* __restrict__ CNT,
    const int* __restrict__ LIST,
    const float* __restrict__ W2_0, const float* __restrict__ W2_1,
    const float* __restrict__ g0, const float* __restrict__ g1,
    float* __restrict__ out)
{
    __shared__ float aS[4][96];
    __shared__ float aV[4][392];   // [c*130 + row] (pad 130 breaks bank stride)
    int tid = threadIdx.x;
    int lane = tid & 63, wave = tid >> 6;
    int n = blockIdx.x*4 + wave;
    bool act = n < N_NODES;              // wave-uniform
    int u_ = lane & 31;
    bool lo = lane < 32;
    int pA = lane >> 5;                  // 0 or 1

    float accM0=0, aV0x=0, aV0y=0, aV0z=0, accM1=0, a12x=0, a12y=0, a12z=0;
    int cnt = 0;
    if (act) { int c = CNT[n]; cnt = c > 64 ? 64 : c; }
    const int* edst = ei + N_EDGES;      // row 1 = edge_dst

    // prefetch edge ids + dst ids (coalesced, one load per lane)
    int e_l = 0, dst_l = 0;
    if (act && cnt > 0) {
        int li = lane < cnt ? lane : cnt - 1;
        e_l = LIST[n*64 + li];
        dst_l = edst[e_l];
    }

    // ---- software-pipelined gather loop ----
    float4 sh_c = make_float4(0,0,0,0), vv_c = sh_c;
    unsigned short w0_c=0, w1_c=0, wA_c=0, w3_c=0;
    float sd_c = 0;
    if (cnt > 0) {
        int e = __shfl(e_l, 0), dst = __shfl(dst_l, 0);
        sh_c = *(const float4*)(esh + (size_t)e*4);
        const __half* wb = WE + (size_t)e*32;
        w0_c = *(const unsigned short*)(wb + (size_t)pA*PL + u_);
        w1_c = *(const unsigned short*)(wb + (size_t)(2+pA)*PL + u_);
        wA_c = *(const unsigned short*)(wb + (size_t)(lo?4:6)*PL + u_);
        w3_c = *(const unsigned short*)(wb + (size_t)5*PL + u_);
        const float* xd = XS + (size_t)dst*192;
        sd_c = xd[lane];
        vv_c = *(const float4*)(xd + 64 + u_*4);
    }
    for (int i = 0; i < cnt; ++i) {
        float4 sh = sh_c, vv = vv_c;
        unsigned short w0u = w0_c, w1u = w1_c, wAu = wA_c, w3u = w3_c;
        float sd = sd_c;
        if (i + 1 < cnt) {
            int e = __shfl(e_l, i+1), dst = __shfl(dst_l, i+1);
            sh_c = *(const float4*)(esh + (size_t)e*4);
            const __half* wb = WE + (size_t)e*32;
            w0_c = *(const unsigned short*)(wb + (size_t)pA*PL + u_);
            w1_c = *(const unsigned short*)(wb + (size_t)(2+pA)*PL + u_);
            wA_c = *(const unsigned short*)(wb + (size_t)(lo?4:6)*PL + u_);
            w3_c = *(const unsigned short*)(wb + (size_t)5*PL + u_);
            const float* xd = XS + (size_t)dst*192;
            sd_c = xd[lane];
            vv_c = *(const float4*)(xd + 64 + u_*4);
        }
        float w0 = __half2float(*(__half*)&w0u);
        float w1 = __half2float(*(__half*)&w1u);
        float wA = __half2float(*(__half*)&wAu);
        float w3 = __half2float(*(__half*)&w3u);
        accM0 += w0*sd*sh.x;                              // m0
        float t1 = w1*sd;                                 // mv0
        aV0x += t1*sh.y; aV0y += t1*sh.z; aV0z += t1*sh.w;
        if (lo) {
            accM1 += w3*(vv.x*sh.y + vv.y*sh.z + vv.z*sh.w);   // m1 (x 1/sqrt3 later)
            a12x += wA*vv.x*sh.x; a12y += wA*vv.y*sh.x; a12z += wA*vv.z*sh.x; // mv1
        } else {                                           // mv2: w4 * cross(vd, sh1)
            a12x += wA*(vv.y*sh.w - vv.z*sh.z);
            a12y += wA*(vv.z*sh.y - vv.x*sh.w);
            a12z += wA*(vv.x*sh.z - vv.y*sh.y);            // (x 1/sqrt2 later)
        }
    }

    const float SEG = 0.25f;                    // 1/sqrt(16)
    const float IS3 = 0.5773502691896258f;      // 1/sqrt(3)
    const float IS2 = 0.7071067811865476f;      // 1/sqrt(2)
    if (act) {
        aS[wave][lane] = accM0 * SEG;
        aV[wave][0*130 + lane] = aV0x * SEG;
        aV[wave][1*130 + lane] = aV0y * SEG;
        aV[wave][2*130 + lane] = aV0z * SEG;
        if (lo) {
            aS[wave][64 + u_] = accM1 * SEG * IS3;
            aV[wave][0*130 + 64 + u_] = a12x * SEG;
            aV[wave][1*130 + 64 + u_] = a12y * SEG;
            aV[wave][2*130 + 64 + u_] = a12z * SEG;
        } else {
            aV[wave][0*130 + 96 + u_] = a12x * SEG * IS2;
            aV[wave][1*130 + 96 + u_] = a12y * SEG * IS2;
            aV[wave][2*130 + 96 + u_] = a12z * SEG * IS2;
        }
    }
    __syncthreads();
    if (!act) return;

    // out_s = ns @ W2_0 / sqrt(96) + sc_s   (W2_0 from L1: coalesced dword)
    float o0=0,o1=0,o2=0,o3=0;
#pragma unroll 4
    for (int k = 0; k < 96; k += 4) {
        o0 += aS[wave][k+0] * W2_0[(k+0)*64 + lane];
        o1 += aS[wave][k+1] * W2_0[(k+1)*64 + lane];
        o2 += aS[wave][k+2] * W2_0[(k+2)*64 + lane];
        o3 += aS[wave][k+3] * W2_0[(k+3)*64 + lane];
    }
    float os = (o0+o1)+(o2+o3);
    const float IS96 = 0.10206207261596575f;  // 1/sqrt(96)
    os = os*IS96 + SC[(size_t)n*192 + lane];

    // out_v[v][c] = sum_u nv[u][c] * W2_1[u][v] / sqrt(128) + sc_v
    int coff = lo ? 0 : 2*130;   // c=0 (lo) / c=2 (hi)
    float p0=0,p1=0,q0=0,q1=0;
#pragma unroll 4
    for (int u = 0; u < 128; u += 2) {
        float wv0 = W2_1[(u+0)*32 + u_];
        float wv1 = W2_1[(u+1)*32 + u_];
        p0 += aV[wave][coff + u+0]*wv0;  q0 += aV[wave][130 + u+0]*wv0;
        p1 += aV[wave][coff + u+1]*wv1;  q1 += aV[wave][130 + u+1]*wv1;
    }
    float ov0 = p0+p1, ov1 = q0+q1;
    const float IS128 = 0.08838834764831845f; // 1/sqrt(128)
    float4 scv = *(const float4*)(SC + (size_t)n*192 + 64 + u_*4);
    float x0 = ov0*IS128 + (lo ? scv.x : scv.z);
    float x1 = ov1*IS128 + scv.y;   // only meaningful for lo lanes

    // RMS norms (full-wave reductions)
    float r = os*os;
#pragma unroll
    for (int off = 32; off > 0; off >>= 1) r += __shfl_xor(r, off);
    float rms_s = sqrtf(r*(1.0f/64.0f) + EPS_F);
    float rv = lo ? (x0*x0 + x1*x1) : (x0*x0);
#pragma unroll
    for (int off = 32; off > 0; off >>= 1) rv += __shfl_xor(rv, off);
    float rms_v = sqrtf(rv*(1.0f/32.0f) + EPS_F);

    float* orow = out + (size_t)n*160;
    orow[lane] = os / rms_s * g0[lane];
    float gv = g1[u_] / rms_v;
    if (lo) {
        orow[64 + u_*3 + 0] = x0 * gv;
        orow[64 + u_*3 + 1] = x1 * gv;
    } else {
        orow[64 + u_*3 + 2] = x0 * gv;
    }
}

// ---------------------------------------------------------------------------
extern "C" void kernel_launch(void* const* d_in, const int* in_sizes, int n_in,
                              void* d_out, int out_size, void* d_ws, size_t ws_size,
                              hipStream_t stream)
{
    const float* nh   = (const float*)d_in[0];
    const int*   ei   = (const int*)  d_in[1];
    const float* esh  = (const float*)d_in[2];
    const float* eat  = (const float*)d_in[3];
    const float* W1_0 = (const float*)d_in[4];
    const float* W1_1 = (const float*)d_in[5];
    const float* Wfc1 = (const float*)d_in[6];
    const float* Wfc2 = (const float*)d_in[7];
    const float* Wfc3 = (const float*)d_in[8];
    const float* W2_0 = (const float*)d_in[9];
    const float* W2_1 = (const float*)d_in[10];
    const float* Wsc0 = (const float*)d_in[11];
    const float* Wsc1 = (const float*)d_in[12];
    const float* g0   = (const float*)d_in[13];
    const float* g1   = (const float*)d_in[14];
    float* out = (float*)d_out;

    // workspace layout — total ~205 MiB
    char* base = (char*)d_ws;
    float*  XS   = (float*)base;                               // N*192 f32   19.2 MB
    float*  SC   = XS + (size_t)N_NODES*192;                   // N*192 f32   19.2 MB
    __half* WE   = (__half*)(SC + (size_t)N_NODES*192);        // 7 planes of E*32 f16 = 179.2 MB
    int*    CNT  = (int*)(WE + (size_t)N_EDGES*224);           // N int        0.1 MB
    int*    LIST = CNT + N_NODES;                              // N*64 int     6.4 MB

    hipMemsetAsync(CNT, 0, N_NODES*sizeof(int), stream);
    k_node_pre  <<<(N_NODES+255)/256, 256, 0, stream>>>(nh, W1_0, W1_1, Wsc0, Wsc1, XS, SC);
    k_build_lists<<<(N_EDGES+255)/256, 256, 0, stream>>>(ei, CNT, LIST);
    k_edge_mlp  <<<(N_EDGES+255)/256, 256, 0, stream>>>(eat, Wfc1, Wfc2, Wfc3, WE);
    k_aggregate <<<(N_NODES+3)/4, 256, 0, stream>>>(ei, esh, WE, XS, SC, CNT, LIST,
                                                    W2_0, W2_1, g0, g1, out);
}

// Round 5
// 406.450 us; speedup vs baseline: 8.6577x; 8.6577x over previous
//
#include <hip/hip_runtime.h>
#include <hip/hip_fp16.h>

#define N_NODES 25000
#define N_EDGES 400000
#define EPS_F 1e-5f
#define EPB 256   // edges per block in k_edge_mlp (4 chunks of 64)

typedef _Float16 f16x8 __attribute__((ext_vector_type(8)));
typedef _Float16 f16x4 __attribute__((ext_vector_type(4)));
typedef float    f32x4 __attribute__((ext_vector_type(4)));

__device__ __forceinline__ float silu_f(float x) {
    return x / (1.0f + __expf(-x));
}

// ---------------------------------------------------------------------------
// K1: per-node linear transforms (unchanged from R3 — not a bottleneck yet).
// XS/SC row layout (stride 192 f32): [0..63]=s, [64 + v*4 + c]=v (c<3, pad).
// ---------------------------------------------------------------------------
__global__ __launch_bounds__(256) void k_node_pre(
    const float* __restrict__ nh,
    const float* __restrict__ W1_0, const float* __restrict__ W1_1,
    const float* __restrict__ Wsc0, const float* __restrict__ Wsc1,
    float* __restrict__ XS, float* __restrict__ SC)
{
    int n = blockIdx.x * 256 + threadIdx.x;
    if (n >= N_NODES) return;
    const float* row = nh + (size_t)n * 160;
    float* xsrow = XS + (size_t)n * 192;
    float* scrow = SC + (size_t)n * 192;

    float si[64];
#pragma unroll
    for (int m = 0; m < 16; ++m) {
        float4 t = *(const float4*)(row + m * 4);
        si[4*m+0] = t.x; si[4*m+1] = t.y; si[4*m+2] = t.z; si[4*m+3] = t.w;
    }
#pragma unroll 1
    for (int jg = 0; jg < 16; ++jg) {
        float a0=0,a1=0,a2=0,a3=0,b0=0,b1=0,b2=0,b3=0;
#pragma unroll
        for (int k = 0; k < 64; ++k) {
            float wa[4]; *(float4*)wa = *(const float4*)(W1_0 + k*64 + jg*4);
            float wb[4]; *(float4*)wb = *(const float4*)(Wsc0 + k*64 + jg*4);
            float s = si[k];
            a0 += s*wa[0]; a1 += s*wa[1]; a2 += s*wa[2]; a3 += s*wa[3];
            b0 += s*wb[0]; b1 += s*wb[1]; b2 += s*wb[2]; b3 += s*wb[3];
        }
        const float sc8 = 0.125f; // 1/sqrt(64)
        *(float4*)(xsrow + jg*4) = make_float4(a0*sc8, a1*sc8, a2*sc8, a3*sc8);
        *(float4*)(scrow + jg*4) = make_float4(b0*sc8, b1*sc8, b2*sc8, b3*sc8);
    }

    float vi[96];
#pragma unroll
    for (int m = 0; m < 24; ++m) {
        float4 t = *(const float4*)(row + 64 + m * 4);
        vi[4*m+0] = t.x; vi[4*m+1] = t.y; vi[4*m+2] = t.z; vi[4*m+3] = t.w;
    }
    const float is32 = 0.17677669529663687f; // 1/sqrt(32)
#pragma unroll 1
    for (int vg = 0; vg < 8; ++vg) {
        float a[4][3], b[4][3];
#pragma unroll
        for (int m = 0; m < 4; ++m) { a[m][0]=a[m][1]=a[m][2]=0.f; b[m][0]=b[m][1]=b[m][2]=0.f; }
#pragma unroll
        for (int u = 0; u < 32; ++u) {
            float wa[4]; *(float4*)wa = *(const float4*)(W1_1 + u*32 + vg*4);
            float wb[4]; *(float4*)wb = *(const float4*)(Wsc1 + u*32 + vg*4);
            float vx = vi[u*3+0], vy = vi[u*3+1], vz = vi[u*3+2];
#pragma unroll
            for (int m = 0; m < 4; ++m) {
                a[m][0] += vx*wa[m]; a[m][1] += vy*wa[m]; a[m][2] += vz*wa[m];
                b[m][0] += vx*wb[m]; b[m][1] += vy*wb[m]; b[m][2] += vz*wb[m];
            }
        }
#pragma unroll
        for (int m = 0; m < 4; ++m) {
            int v = vg*4 + m;
            *(float4*)(xsrow + 64 + v*4) = make_float4(a[m][0]*is32, a[m][1]*is32, a[m][2]*is32, 0.f);
            *(float4*)(scrow + 64 + v*4) = make_float4(b[m][0]*is32, b[m][1]*is32, b[m][2]*is32, 0.f);
        }
    }
}

// ---------------------------------------------------------------------------
// K2: per-src edge lists. Only int atomics (400k).
// ---------------------------------------------------------------------------
__global__ __launch_bounds__(256) void k_build_lists(
    const int* __restrict__ ei, int* __restrict__ CNT, int* __restrict__ LIST)
{
    int e = blockIdx.x * 256 + threadIdx.x;
    if (e >= N_EDGES) return;
    int src = ei[e];                       // row 0 = edge_src
    int pos = atomicAdd(&CNT[src], 1);
    if (pos < 64) LIST[src*64 + pos] = e;
}

// ---------------------------------------------------------------------------
// K3: edge MLP via fp16 MFMA (16x16x32). Computes D = W^T · h^T so the C/D
// fragment (col=lane&15=EDGE, row=quad*4+r=CHANNEL) gives each lane 4
// consecutive channels of one edge -> 8-B packed LDS/global stores.
// A-operand = transposed weights, pre-packed per-fragment in LDS (f16).
// B-operand = activations [edge][k], contiguous ds_read_b128.
// Each wave owns a 16-edge slice; h1/h2 LDS round-trips are wave-private
// (no barriers); only avb staging needs syncthreads. 4 chunks/block.
// ---------------------------------------------------------------------------
__global__ __launch_bounds__(256, 2) void k_edge_mlp(
    const float* __restrict__ eat,
    const float* __restrict__ Wfc1, const float* __restrict__ Wfc2,
    const float* __restrict__ Wfc3,
    _Float16* __restrict__ WE)
{
    __shared__ _Float16 sA1[4*64*8];    //  4 KB  layer-1 A-frags (k>=8 zero)
    __shared__ _Float16 sA2[8*64*8];    //  8 KB  layer-2 A-frags
    __shared__ _Float16 sA3[28*64*8];   // 28 KB  layer-3 A-frags
    __shared__ _Float16 avb[64*40];     //  5 KB  edge_attr f16, k 8..31 zeroed
    __shared__ _Float16 h1b[64*72];     //  9 KB  (72-half row pad)
    __shared__ _Float16 h2b[64*72];     //  9 KB

    const int tid  = threadIdx.x;
    const int lane = tid & 63, wv = tid >> 6;
    const int q = lane >> 4, col = lane & 15;

    // ---- one-time per-block A-fragment staging (weights -> f16, packed) ----
    {   // sA1: A[m][k] = Wfc1^T, only k<8 nonzero (K padded to 32 with zeros)
        int nt = tid >> 6, L = tid & 63, qq = L >> 4, cc = L & 15;
        _Float16* dst = &sA1[tid*8];
        if (qq == 0) {
#pragma unroll
            for (int j = 0; j < 8; ++j) dst[j] = (_Float16)Wfc1[j*64 + nt*16 + cc];
        } else {
#pragma unroll
            for (int j = 0; j < 8; ++j) dst[j] = (_Float16)0.f;
        }
    }
    for (int t = tid; t < 512; t += 256) {
        int tile = t >> 6, ks = tile >> 2, nt = tile & 3;
        int L = t & 63, qq = L >> 4, cc = L & 15;
        int kb = ks*32 + qq*8;
        _Float16* dst = &sA2[t*8];
#pragma unroll
        for (int j = 0; j < 8; ++j) dst[j] = (_Float16)Wfc2[(kb+j)*64 + nt*16 + cc];
    }
    for (int t = tid; t < 1792; t += 256) {
        int tile = t >> 6, ks = tile / 14, nt = tile - ks*14;
        int L = t & 63, qq = L >> 4, cc = L & 15;
        int kb = ks*32 + qq*8;
        _Float16* dst = &sA3[t*8];
#pragma unroll
        for (int j = 0; j < 8; ++j) dst[j] = (_Float16)Wfc3[(kb+j)*224 + nt*16 + cc];
    }
    // zero avb k=8..31 (REQUIRED: 0-weight x NaN-garbage = NaN)
    for (int idx = tid; idx < 64*12; idx += 256) {
        int e = idx / 12, s = idx - e*12;
        *(unsigned int*)&avb[e*40 + 8 + s*2] = 0u;
    }

    const float IS8 = 0.35355339059327373f;  // 1/sqrt(8)
    size_t base = (size_t)blockIdx.x * EPB;
    const int erow = wv*16 + col;            // this lane's edge row in chunk

#pragma unroll 1
    for (int c = 0; c < EPB/64; ++c) {
        size_t cb = base + (size_t)c*64;
        __syncthreads();                     // prior chunk's avb readers done
        if (tid < 128) {                     // stage 64 edges x 8 attrs -> f16
            int e = tid >> 1, part = tid & 1;
            size_t eg = cb + e; if (eg >= N_EDGES) eg = N_EDGES - 1;
            float4 v = *(const float4*)(eat + eg*8 + part*4);
            f16x4 p; p[0]=(_Float16)v.x; p[1]=(_Float16)v.y; p[2]=(_Float16)v.z; p[3]=(_Float16)v.w;
            *(f16x4*)&avb[e*40 + part*4] = p;
        }
        __syncthreads();

        // ---- layer 1: 8 -> 64 (K zero-padded to 32), silu ----
        f16x8 b1 = *(const f16x8*)&avb[erow*40 + q*8];
#pragma unroll
        for (int nt = 0; nt < 4; ++nt) {
            f32x4 acc = {0.f,0.f,0.f,0.f};
            f16x8 a = *(const f16x8*)&sA1[(nt*64 + lane)*8];
            acc = __builtin_amdgcn_mfma_f32_16x16x32_f16(a, b1, acc, 0, 0, 0);
            f16x4 p;
#pragma unroll
            for (int r = 0; r < 4; ++r) p[r] = (_Float16)silu_f(acc[r]*IS8);
            *(f16x4*)&h1b[erow*72 + nt*16 + q*4] = p;   // wave-private rows
        }
        // ---- layer 2: 64 -> 64, silu ----
#pragma unroll
        for (int nt = 0; nt < 4; ++nt) {
            f32x4 acc = {0.f,0.f,0.f,0.f};
#pragma unroll
            for (int ks = 0; ks < 2; ++ks) {
                f16x8 a = *(const f16x8*)&sA2[((ks*4+nt)*64 + lane)*8];
                f16x8 b = *(const f16x8*)&h1b[erow*72 + ks*32 + q*8];
                acc = __builtin_amdgcn_mfma_f32_16x16x32_f16(a, b, acc, 0, 0, 0);
            }
            f16x4 p;
#pragma unroll
            for (int r = 0; r < 4; ++r) p[r] = (_Float16)silu_f(acc[r]*0.125f);
            *(f16x4*)&h2b[erow*72 + nt*16 + q*4] = p;
        }
        // ---- layer 3: 64 -> 224, direct packed global store ----
        size_t eg = cb + erow;
        bool wrb = eg < N_EDGES;
#pragma unroll 1
        for (int nt = 0; nt < 14; ++nt) {
            f32x4 acc = {0.f,0.f,0.f,0.f};
#pragma unroll
            for (int ks = 0; ks < 2; ++ks) {
                f16x8 a = *(const f16x8*)&sA3[((ks*14+nt)*64 + lane)*8];
                f16x8 b = *(const f16x8*)&h2b[erow*72 + ks*32 + q*8];
                acc = __builtin_amdgcn_mfma_f32_16x16x32_f16(a, b, acc, 0, 0, 0);
            }
            f16x4 p;
#pragma unroll
            for (int r = 0; r < 4; ++r) p[r] = (_Float16)(acc[r]*0.125f);
            if (wrb) *(f16x4*)&WE[eg*224 + nt*16 + q*4] = p;  // 4 consecutive channels
        }
    }
}

// ---------------------------------------------------------------------------
// K4: wave-per-node gather + tensor product + segment sum (register
// accumulators, NO float atomics), software-pipelined; row-major WE reads
// (coalesced across lanes). Epilogue GEMMs read W2 from L1.
// ---------------------------------------------------------------------------
__global__ __launch_bounds__(256) void k_aggregate(
    const int* __restrict__ ei, const float* __restrict__ esh,
    const _Float16* __restrict__ WE, const float* __restrict__ XS,
    const float* __restrict__ SC, const int* __restrict__ CNT,
    const int* __restrict__ LIST,
    const float* __restrict__ W2_0, const float* __restrict__ W2_1,
    const float* __restrict__ g0, const float* __restrict__ g1,
    float* __restrict__ out)
{
    __shared__ float aS[4][96];
    __shared__ float aV[4][392];   // [c*130 + row]
    int tid = threadIdx.x;
    int lane = tid & 63, wave = tid >> 6;
    int n = blockIdx.x*4 + wave;
    bool act = n < N_NODES;              // wave-uniform
    int u_ = lane & 31;
    bool lo = lane < 32;

    float accM0=0, aV0x=0, aV0y=0, aV0z=0, accM1=0, a12x=0, a12y=0, a12z=0;
    int cnt = 0;
    if (act) { int c = CNT[n]; cnt = c > 64 ? 64 : c; }
    const int* edst = ei + N_EDGES;      // row 1 = edge_dst

    int e_l = 0, dst_l = 0;
    if (act && cnt > 0) {
        int li = lane < cnt ? lane : cnt - 1;
        e_l = LIST[n*64 + li];
        dst_l = edst[e_l];
    }

    float4 sh_c = make_float4(0,0,0,0), vv_c = sh_c;
    unsigned short w0_c=0, w1_c=0, wA_c=0, w3_c=0;
    float sd_c = 0;
    if (cnt > 0) {
        int e = __shfl(e_l, 0), dst = __shfl(dst_l, 0);
        sh_c = *(const float4*)(esh + (size_t)e*4);
        const _Float16* wr = WE + (size_t)e*224;
        w0_c = *(const unsigned short*)(wr + lane);
        w1_c = *(const unsigned short*)(wr + 64 + lane);
        wA_c = *(const unsigned short*)(wr + (lo ? 128 : 192) + u_);
        w3_c = *(const unsigned short*)(wr + 160 + u_);
        const float* xd = XS + (size_t)dst*192;
        sd_c = xd[lane];
        vv_c = *(const float4*)(xd + 64 + u_*4);
    }
    for (int i = 0; i < cnt; ++i) {
        float4 sh = sh_c, vv = vv_c;
        unsigned short w0u = w0_c, w1u = w1_c, wAu = wA_c, w3u = w3_c;
        float sd = sd_c;
        if (i + 1 < cnt) {
            int e = __shfl(e_l, i+1), dst = __shfl(dst_l, i+1);
            sh_c = *(const float4*)(esh + (size_t)e*4);
            const _Float16* wr = WE + (size_t)e*224;
            w0_c = *(const unsigned short*)(wr + lane);
            w1_c = *(const unsigned short*)(wr + 64 + lane);
            wA_c = *(const unsigned short*)(wr + (lo ? 128 : 192) + u_);
            w3_c = *(const unsigned short*)(wr + 160 + u_);
            const float* xd = XS + (size_t)dst*192;
            sd_c = xd[lane];
            vv_c = *(const float4*)(xd + 64 + u_*4);
        }
        float w0 = (float)*(const _Float16*)&w0u;
        float w1 = (float)*(const _Float16*)&w1u;
        float wA = (float)*(const _Float16*)&wAu;
        float w3 = (float)*(const _Float16*)&w3u;
        accM0 += w0*sd*sh.x;                              // m0
        float t1 = w1*sd;                                 // mv0
        aV0x += t1*sh.y; aV0y += t1*sh.z; aV0z += t1*sh.w;
        if (lo) {
            accM1 += w3*(vv.x*sh.y + vv.y*sh.z + vv.z*sh.w);   // m1
            a12x += wA*vv.x*sh.x; a12y += wA*vv.y*sh.x; a12z += wA*vv.z*sh.x; // mv1
        } else {                                           // mv2: w4 * cross(vd, sh1)
            a12x += wA*(vv.y*sh.w - vv.z*sh.z);
            a12y += wA*(vv.z*sh.y - vv.x*sh.w);
            a12z += wA*(vv.x*sh.z - vv.y*sh.y);
        }
    }

    const float SEG = 0.25f;                    // 1/sqrt(16)
    const float IS3 = 0.5773502691896258f;      // 1/sqrt(3)
    const float IS2 = 0.7071067811865476f;      // 1/sqrt(2)
    if (act) {
        aS[wave][lane] = accM0 * SEG;
        aV[wave][0*130 + lane] = aV0x * SEG;
        aV[wave][1*130 + lane] = aV0y * SEG;
        aV[wave][2*130 + lane] = aV0z * SEG;
        if (lo) {
            aS[wave][64 + u_] = accM1 * SEG * IS3;
            aV[wave][0*130 + 64 + u_] = a12x * SEG;
            aV[wave][1*130 + 64 + u_] = a12y * SEG;
            aV[wave][2*130 + 64 + u_] = a12z * SEG;
        } else {
            aV[wave][0*130 + 96 + u_] = a12x * SEG * IS2;
            aV[wave][1*130 + 96 + u_] = a12y * SEG * IS2;
            aV[wave][2*130 + 96 + u_] = a12z * SEG * IS2;
        }
    }
    __syncthreads();
    if (!act) return;

    // out_s = ns @ W2_0 / sqrt(96) + sc_s
    float o0=0,o1=0,o2=0,o3=0;
#pragma unroll 4
    for (int k = 0; k < 96; k += 4) {
        o0 += aS[wave][k+0] * W2_0[(k+0)*64 + lane];
        o1 += aS[wave][k+1] * W2_0[(k+1)*64 + lane];
        o2 += aS[wave][k+2] * W2_0[(k+2)*64 + lane];
        o3 += aS[wave][k+3] * W2_0[(k+3)*64 + lane];
    }
    float os = (o0+o1)+(o2+o3);
    const float IS96 = 0.10206207261596575f;  // 1/sqrt(96)
    os = os*IS96 + SC[(size_t)n*192 + lane];

    // out_v[v][c] = sum_u nv[u][c] * W2_1[u][v] / sqrt(128) + sc_v
    int coff = lo ? 0 : 2*130;
    float p0=0,p1=0,q0=0,q1=0;
#pragma unroll 4
    for (int u = 0; u < 128; u += 2) {
        float wv0 = W2_1[(u+0)*32 + u_];
        float wv1 = W2_1[(u+1)*32 + u_];
        p0 += aV[wave][coff + u+0]*wv0;  q0 += aV[wave][130 + u+0]*wv0;
        p1 += aV[wave][coff + u+1]*wv1;  q1 += aV[wave][130 + u+1]*wv1;
    }
    float ov0 = p0+p1, ov1 = q0+q1;
    const float IS128 = 0.08838834764831845f; // 1/sqrt(128)
    float4 scv = *(const float4*)(SC + (size_t)n*192 + 64 + u_*4);
    float x0 = ov0*IS128 + (lo ? scv.x : scv.z);
    float x1 = ov1*IS128 + scv.y;

    float r = os*os;
#pragma unroll
    for (int off = 32; off > 0; off >>= 1) r += __shfl_xor(r, off);
    float rms_s = sqrtf(r*(1.0f/64.0f) + EPS_F);
    float rv = lo ? (x0*x0 + x1*x1) : (x0*x0);
#pragma unroll
    for (int off = 32; off > 0; off >>= 1) rv += __shfl_xor(rv, off);
    float rms_v = sqrtf(rv*(1.0f/32.0f) + EPS_F);

    float* orow = out + (size_t)n*160;
    orow[lane] = os / rms_s * g0[lane];
    float gv = g1[u_] / rms_v;
    if (lo) {
        orow[64 + u_*3 + 0] = x0 * gv;
        orow[64 + u_*3 + 1] = x1 * gv;
    } else {
        orow[64 + u_*3 + 2] = x0 * gv;
    }
}

// ---------------------------------------------------------------------------
extern "C" void kernel_launch(void* const* d_in, const int* in_sizes, int n_in,
                              void* d_out, int out_size, void* d_ws, size_t ws_size,
                              hipStream_t stream)
{
    const float* nh   = (const float*)d_in[0];
    const int*   ei   = (const int*)  d_in[1];
    const float* esh  = (const float*)d_in[2];
    const float* eat  = (const float*)d_in[3];
    const float* W1_0 = (const float*)d_in[4];
    const float* W1_1 = (const float*)d_in[5];
    const float* Wfc1 = (const float*)d_in[6];
    const float* Wfc2 = (const float*)d_in[7];
    const float* Wfc3 = (const float*)d_in[8];
    const float* W2_0 = (const float*)d_in[9];
    const float* W2_1 = (const float*)d_in[10];
    const float* Wsc0 = (const float*)d_in[11];
    const float* Wsc1 = (const float*)d_in[12];
    const float* g0   = (const float*)d_in[13];
    const float* g1   = (const float*)d_in[14];
    float* out = (float*)d_out;

    // workspace layout — total ~205 MiB
    char* base = (char*)d_ws;
    float*     XS   = (float*)base;                            // N*192 f32   19.2 MB
    float*     SC   = XS + (size_t)N_NODES*192;                // N*192 f32   19.2 MB
    _Float16*  WE   = (_Float16*)(SC + (size_t)N_NODES*192);   // E*224 f16  179.2 MB (row-major)
    int*       CNT  = (int*)(WE + (size_t)N_EDGES*224);        // N int        0.1 MB
    int*       LIST = CNT + N_NODES;                           // N*64 int     6.4 MB

    hipMemsetAsync(CNT, 0, N_NODES*sizeof(int), stream);
    k_node_pre  <<<(N_NODES+255)/256, 256, 0, stream>>>(nh, W1_0, W1_1, Wsc0, Wsc1, XS, SC);
    k_build_lists<<<(N_EDGES+255)/256, 256, 0, stream>>>(ei, CNT, LIST);
    k_edge_mlp  <<<(N_EDGES+EPB-1)/EPB, 256, 0, stream>>>(eat, Wfc1, Wfc2, Wfc3, WE);
    k_aggregate <<<(N_NODES+3)/4, 256, 0, stream>>>(ei, esh, WE, XS, SC, CNT, LIST,
                                                    W2_0, W2_1, g0, g1, out);
}